// Round 1
// 202.563 us; speedup vs baseline: 1.0600x; 1.0600x over previous
//
#include <hip/hip_runtime.h>

// ---------- common helpers ----------
typedef __attribute__((ext_vector_type(8))) unsigned short ushort8v;
typedef __attribute__((ext_vector_type(8))) __bf16 bf16x8;
typedef __attribute__((ext_vector_type(4))) float floatx4;

__device__ __forceinline__ unsigned short f2b(float f) {
    unsigned u = __float_as_uint(f);
    unsigned r = u + 0x7fffu + ((u >> 16) & 1u);   // RNE
    return (unsigned short)(r >> 16);
}
__device__ __forceinline__ float b2f(unsigned short h) {
    return __uint_as_float(((unsigned)h) << 16);
}

// global -> LDS direct (16B/lane). Dest must be wave-uniform base + lane*16.
__device__ __forceinline__ void gload16(const unsigned short* g, unsigned short* l) {
    __builtin_amdgcn_global_load_lds(
        (const __attribute__((address_space(1))) unsigned int*)g,
        (__attribute__((address_space(3))) unsigned int*)l,
        16, 0, 0);
}

// ============================================================================
// Fragment-swizzled layout: tensor [T16][KC][16][8] bf16;
//   elem (t16, kc, l, e) = Mat[t16*16 + l][kc*8 + e]
// MFMA 16x16x32 fragment at kc0: lane(quad,l16) reads 16B at
//   ((t16*KC + kc0 + quad)*16 + l16)*16 B -> 64 lanes = 1KB contiguous.
// R9: gemm rebuilt as m97-style LDS-staged kernel. R8's register double-buffer
// was latency-bound: 1 wave/SIMD (512 blk x 2 waves), ~1900 cyc exposed L3
// latency per K-iter (768 MB of L2/L3 panel traffic: B re-read 128x/wave).
// Now: 128x128 block tile, 256 thr (2x2 waves of 64x64), BK=64,
// double-buffered LDS via global_load_lds (swizzled layout => linear dest),
// 2-phase stage-ahead loop. 64KB LDS -> 2 blocks/CU = 2 waves/SIMD.
// ============================================================================

// ---------- fused prep ----------
// blocks [0,2048):      x (8192x2048 f32) -> A2x swizzled bf16 (KC=256)
// blocks [2048,4096):   W (2048x1023 f32) -> B2w swizzled bf16 (KC=256)
// blocks [4096,5120):   softmax(leaf_dist) -> B2p swizzled bf16 (KC=128), c>=1000 zero
__global__ __launch_bounds__(256) void prep_kernel(const float* __restrict__ x,
                                                   unsigned short* __restrict__ A2x,
                                                   const float* __restrict__ W,
                                                   unsigned short* __restrict__ B2w,
                                                   const float* __restrict__ ld_,
                                                   unsigned short* __restrict__ B2p) {
    __shared__ float tile[32 * 33];
    __shared__ float buf[1000];
    __shared__ float red[8];
    const int b = blockIdx.x, t = threadIdx.x;
    if (b < 2048) {                        // ---- cvt+swizzle x: quarter of a 16-row slab ----
        const int mt = b >> 2, kq = (b & 3) * 64;
        const int kco = t >> 4, l16 = t & 15;       // kco 0..15
        const float* xr0 = x + (size_t)(mt * 16 + l16) * 2048;
#pragma unroll
        for (int i = 0; i < 4; i++) {
            const int kc = kq + i * 16 + kco;
            const float* xr = xr0 + kc * 8;
            float4 v0 = *(const float4*)xr;
            float4 v1 = *(const float4*)(xr + 4);
            ushort8v o;
            o[0] = f2b(v0.x); o[1] = f2b(v0.y); o[2] = f2b(v0.z); o[3] = f2b(v0.w);
            o[4] = f2b(v1.x); o[5] = f2b(v1.y); o[6] = f2b(v1.z); o[7] = f2b(v1.w);
            *(ushort8v*)(A2x + ((size_t)(mt * 256 + kc) * 16 + l16) * 8) = o;
        }
    } else if (b < 4096) {                 // ---- transpose+swizzle W ----
        const int idx = b - 2048;
        const int n0 = (idx & 31) * 32, k0 = (idx >> 5) * 32;
        const int tx = t & 31, ty = t >> 5;
#pragma unroll
        for (int i = 0; i < 4; i++) {
            int k = k0 + ty + i * 8, n = n0 + tx;
            tile[(ty + i * 8) * 33 + tx] = (n < 1023) ? W[(size_t)k * 1023 + n] : 0.f;
        }
        __syncthreads();
#pragma unroll
        for (int i = 0; i < 4; i++) {
            int n = n0 + ty + i * 8, k = k0 + tx;
            size_t off = ((size_t)((n >> 4) * 256 + (k >> 3)) * 16 + (n & 15)) * 8 + (k & 7);
            B2w[off] = f2b(tile[tx * 33 + ty + i * 8]);
        }
    } else {                               // ---- softmax -> B2p swizzled (+zero pad) ----
        const int l0 = b - 4096;
        const float* r = ld_ + (size_t)l0 * 1000;
        float mx = -3.4e38f;
        for (int i = t; i < 1000; i += 256) { float v = r[i]; buf[i] = v; mx = fmaxf(mx, v); }
#pragma unroll
        for (int o = 32; o > 0; o >>= 1) mx = fmaxf(mx, __shfl_down(mx, o));
        if ((t & 63) == 0) red[t >> 6] = mx;
        __syncthreads();
        mx = fmaxf(fmaxf(red[0], red[1]), fmaxf(red[2], red[3]));
        float s = 0.f;
        for (int i = t; i < 1000; i += 256) { float e = __expf(buf[i] - mx); buf[i] = e; s += e; }
#pragma unroll
        for (int o = 32; o > 0; o >>= 1) s += __shfl_down(s, o);
        if ((t & 63) == 0) red[4 + (t >> 6)] = s;
        __syncthreads();
        float inv = 1.f / (red[4] + red[5] + red[6] + red[7]);
        for (int i = t; i < 1024; i += 256) {
            float pv = (i < 1000) ? buf[i] * inv : 0.f;
            size_t off = ((size_t)((i >> 4) * 128 + (l0 >> 3)) * 16 + (i & 15)) * 8 + (l0 & 7);
            B2p[off] = f2b(pv);
        }
    }
}

// ---------- pp: 8 rows per block (barriers amortized), writes A2p swizzled ----------
// LDS: d 8x1024 bf16 (16KB) + pa/pb 8x1024 f32 (64KB) = 80KB -> 2 blocks/CU.
__global__ __launch_bounds__(256) void pp_kernel(const unsigned short* __restrict__ dec,
                                                 unsigned short* __restrict__ A2p) {
    __shared__ unsigned short dsh[8 * 1024];
    __shared__ float pa[8 * 1024];
    __shared__ float pb[8 * 1024];
    const int t = threadIdx.x;
    const int r0 = blockIdx.x * 8;
    // load 8 rows of dec (16KB contiguous) as ushort8
    {
        const ushort8v* src = (const ushort8v*)(dec + (size_t)r0 * 1024);
        ushort8v* dst = (ushort8v*)dsh;
        for (int g = t; g < 1024; g += 256) dst[g] = src[g];
    }
    if (t < 8) pa[t * 1024] = 1.f;
    __syncthreads();
    float* cur = pa; float* nxt = pb;
    for (int dep = 0; dep < 10; dep++) {
        const int half = 1 << dep;
        const int len  = half << 1;
        const int total = len << 3;        // 8 rows
        for (int idx = t; idx < total; idx += 256) {
            const int r = idx >> (dep + 1);
            const int j = idx & (len - 1);
            int tt = j >> dep;
            int s  = j & (half - 1);
            int i2 = 2 * s + tt;
            int u  = i2 >> dep;
            int rr = i2 & (half - 1);
            float dv = b2f(dsh[r * 1024 + half - 1 + rr]);
            nxt[r * 1024 + j] = cur[r * 1024 + rr] * (u ? (1.f - dv) : dv);
        }
        __syncthreads();
        float* tmp = cur; cur = nxt; nxt = tmp;
    }
    // write swizzled A2p (KC=128): off(row, j)
    for (int i = t; i < 8192; i += 256) {
        const int r = i >> 10, j = i & 1023;
        const int rrow = r0 + r;
        size_t off = ((size_t)((rrow >> 4) * 128 + (j >> 3)) * 16 + (rrow & 15)) * 8 + (j & 7);
        A2p[off] = f2b(cur[r * 1024 + j]);
    }
}

// ---------- m97-style LDS-staged bf16 GEMM ----------
// Block tile 128x128, 256 thr = 4 waves (2x2), wave tile 64x64 (4x4 frags).
// BK=64 = 8 kc-chunks; LDS tile per matrix = 64 chunks x 256B = 16KB,
// double-buffered: 2*(16+16) = 64KB -> 2 blocks/CU (grid 512 = 2/CU anyway).
// Stage: global_load_lds width=16; swizzled layout => LDS dest is linear
// wave-uniform base + lane*16, source is contiguous 1KB per wave-issue.
// 2-phase loop: STAGE(next) -> compute(cur) -> __syncthreads (vmcnt drain).
// XCD swizzle: xcd g owns bm-tiles [8g,8g+8) for all 8 bn.
// EPI 0: sigmoid(acc+bias[col]) -> bf16 ld=1024. EPI 1: f32, col<1000.
template <int EPI>
__global__ __launch_bounds__(256, 2) void gemm_lds(const unsigned short* __restrict__ A2,
                                                   const unsigned short* __restrict__ B2,
                                                   const float* __restrict__ bias,
                                                   unsigned short* __restrict__ obf,
                                                   float* __restrict__ of32,
                                                   int KC, int ldo) {
    __shared__ unsigned short ldsA[2][8192];   // 64 chunks * 128 ushorts, x2 bufs
    __shared__ unsigned short ldsB[2][8192];

    const int tid  = threadIdx.x;
    const int lane = tid & 63;
    const int wave = tid >> 6;
    const int quad = lane >> 4, l16 = lane & 15;
    const int wr = wave >> 1, wc = wave & 1;   // 2x2 wave grid

    const int l   = blockIdx.x;
    const int xcd = l & 7;
    const int j   = l >> 3;                    // 0..63
    const int bm  = xcd * 8 + (j & 7);         // 128-row tile idx 0..63
    const int bn  = j >> 3;                    // 128-col tile idx 0..7

    // ---- staging map: chunk c = i*16 + (tid>>4); (mi,kcq) = (c>>3, c&7) ----
    const int cBase = tid >> 4;                // 0..15
    const int sub   = (tid & 15) * 8;          // ushort offset inside 256B chunk
    const unsigned short* srcA[4];
    const unsigned short* srcB[4];
#pragma unroll
    for (int i = 0; i < 4; i++) {
        const int c  = i * 16 + cBase;
        const int mi = c >> 3, kcq = c & 7;
        srcA[i] = A2 + ((size_t)(bm * 8 + mi) * KC + kcq) * 128 + sub;
        srcB[i] = B2 + ((size_t)(bn * 8 + mi) * KC + kcq) * 128 + sub;
    }

    floatx4 acc[4][4] = {};
    const int nks = KC >> 3;                   // BK=64 -> 8 chunks/step

    // prologue: stage step 0 into buf 0
#pragma unroll
    for (int i = 0; i < 4; i++) {
        const int c = i * 16 + cBase;
        gload16(srcA[i], &ldsA[0][c * 128 + sub]);
        gload16(srcB[i], &ldsB[0][c * 128 + sub]);
    }
    __syncthreads();                           // vmcnt(0) drain + barrier

    int buf = 0;
    for (int ks = 0; ks < nks; ks++) {
        // issue next-step stage first (overlaps with ds_read+MFMA below)
        if (ks + 1 < nks) {
            const size_t ko = (size_t)(ks + 1) * 1024;   // 8 chunks * 128 ushorts
#pragma unroll
            for (int i = 0; i < 4; i++) {
                const int c = i * 16 + cBase;
                gload16(srcA[i] + ko, &ldsA[buf ^ 1][c * 128 + sub]);
                gload16(srcB[i] + ko, &ldsB[buf ^ 1][c * 128 + sub]);
            }
        }
        // compute current buffer: 2 k-slices of 32, 32 MFMAs/wave
#pragma unroll
        for (int kk = 0; kk < 2; kk++) {
            bf16x8 af[4], bfv[4];
#pragma unroll
            for (int m2 = 0; m2 < 4; m2++)
                af[m2] = __builtin_bit_cast(bf16x8,
                    *(const ushort8v*)&ldsA[buf][((wr * 4 + m2) * 8 + kk * 4 + quad) * 128 + l16 * 8]);
#pragma unroll
            for (int n2 = 0; n2 < 4; n2++)
                bfv[n2] = __builtin_bit_cast(bf16x8,
                    *(const ushort8v*)&ldsB[buf][((wc * 4 + n2) * 8 + kk * 4 + quad) * 128 + l16 * 8]);
#pragma unroll
            for (int m2 = 0; m2 < 4; m2++)
#pragma unroll
                for (int n2 = 0; n2 < 4; n2++)
                    acc[m2][n2] = __builtin_amdgcn_mfma_f32_16x16x32_bf16(
                        af[m2], bfv[n2], acc[m2][n2], 0, 0, 0);
        }
        __syncthreads();                       // drains stage vmcnt + LDS reuse fence
        buf ^= 1;
    }

    // ---- epilogue ----
    const int mt0 = bm * 8 + wr * 4;
    const int nt0 = bn * 8 + wc * 4;
#pragma unroll
    for (int n2 = 0; n2 < 4; n2++) {
        const int col = (nt0 + n2) * 16 + l16;
        float bb = 0.f;
        if constexpr (EPI == 0) bb = (col < 1023) ? bias[col] : 0.f;
#pragma unroll
        for (int m2 = 0; m2 < 4; m2++) {
            const int row0 = (mt0 + m2) * 16 + quad * 4;
#pragma unroll
            for (int r = 0; r < 4; r++) {
                float v = acc[m2][n2][r];
                if constexpr (EPI == 0) {
                    float sgm = 1.f / (1.f + __expf(-(v + bb)));
                    obf[(size_t)(row0 + r) * ldo + col] = f2b(sgm);
                } else {
                    if (col < 1000) of32[(size_t)(row0 + r) * ldo + col] = v;
                }
            }
        }
    }
}

// ---------- host ----------
extern "C" void kernel_launch(void* const* d_in, const int* in_sizes, int n_in,
                              void* d_out, int out_size, void* d_ws, size_t ws_size,
                              hipStream_t stream) {
    const float* x   = (const float*)d_in[0];   // 8192x2048
    const float* W   = (const float*)d_in[1];   // 2048x1023
    const float* b   = (const float*)d_in[2];   // 1023
    const float* ldd = (const float*)d_in[3];   // 1024x1000
    float* out = (float*)d_out;                 // 8192x1000

    char* ws = (char*)d_ws;
    unsigned short* A2x = (unsigned short*)(ws);              // 33,554,432 B (swizzled x bf16)
    unsigned short* A2p = (unsigned short*)(ws);              // overlay: pp output (A2x dead by then)
    unsigned short* B2w = (unsigned short*)(ws + 33554432);   // 4,194,304 B (swizzled W^T)
    unsigned short* dec = (unsigned short*)(ws + 37748736);   // 16,777,216 B (row-major decisions)
    unsigned short* B2p = (unsigned short*)(ws + 54525952);   // 2,097,152 B (swizzled P^T)

    // prep: x-swizzle | W-transpose-swizzle | softmax->swizzle (independent)
    prep_kernel<<<5120, 256, 0, stream>>>(x, A2x, W, B2w, ldd, B2p);
    // decisions = sigmoid(x@W + b), row-major bf16 (cols padded to 1024)
    gemm_lds<0><<<512, 256, 0, stream>>>(A2x, B2w, b, dec, nullptr, 256, 1024);
    // pp (reference-literal order), 8 rows/block, writes swizzled A2p
    pp_kernel<<<1024, 256, 0, stream>>>(dec, A2p);
    // out = pp @ P
    gemm_lds<1><<<512, 256, 0, stream>>>(A2p, B2p, nullptr, nullptr, out, 128, 1000);
}